// Round 1
// baseline (2622.536 us; speedup 1.0000x reference)
//
#include <hip/hip_runtime.h>
#include <stdint.h>

// Problem constants (from reference):
#define B_ROWS   2048
#define N_COLS   150000
#define NSTRIPS  128
#define CHUNK    128
#define NCHUNK   ((N_COLS + CHUNK - 1) / CHUNK)   // 1172 (last chunk has 112 cols)
#define ROWG     (B_ROWS / 128)                   // 16 row groups of 128 rows

#define NEG_HUGE (-3.0e38f)

// ---------------- threefry2x32, key = (0, 42) = jax.random.key(42) ----------
__device__ __forceinline__ uint32_t rotl32(uint32_t x, int r) {
  return (x << r) | (x >> (32 - r));
}

__device__ __forceinline__ void threefry2x32_k42(uint32_t& x0, uint32_t& x1) {
  const uint32_t ks0 = 0u;
  const uint32_t ks1 = 42u;
  const uint32_t ks2 = 0x1BD11BDAu ^ 0u ^ 42u;  // 0x1BD11BF0
  x0 += ks0; x1 += ks1;
#define TF_R(r) { x0 += x1; x1 = rotl32(x1, (r)); x1 ^= x0; }
  TF_R(13) TF_R(15) TF_R(26) TF_R(6)
  x0 += ks1; x1 += ks2 + 1u;
  TF_R(17) TF_R(29) TF_R(16) TF_R(24)
  x0 += ks2; x1 += ks0 + 2u;
  TF_R(13) TF_R(15) TF_R(26) TF_R(6)
  x0 += ks0; x1 += ks1 + 3u;
  TF_R(17) TF_R(29) TF_R(16) TF_R(24)
  x0 += ks1; x1 += ks2 + 4u;
  TF_R(13) TF_R(15) TF_R(26) TF_R(6)
  x0 += ks2; x1 += ks0 + 5u;
#undef TF_R
}

// u = (bits>>9 | one_bits) as float - 1.0 ; 0 -> tiny ; g = -log(-log(u))
// Inner log via log1pf(f-1) (argument exact): accurate for u -> 1, which is
// exactly where the argmax winners live.
__device__ __forceinline__ float gumbel_from_bits(uint32_t bits) {
  const uint32_t mant = bits >> 9;
  const float f = __uint_as_float(mant | 0x3f800000u) - 1.0f;  // exact
  const float l1 = mant ? log1pf(f - 1.0f) : -87.33654475055311f;  // ln(u); ln(tiny) for 0
  return -__logf(-l1);
}

// RNG VARIANT A: jax_threefry_partitionable=True (default in jax >= 0.5):
//   counter = (hi=0, lo=flat_index); 32-bit draw = out0 ^ out1 (xor-fold).
// Fallbacks if samples mismatch: out0-only; legacy split-half counters.
__device__ __forceinline__ float gumbel_at(uint32_t flat_idx) {
  uint32_t x0 = 0u, x1 = flat_idx;
  threefry2x32_k42(x0, x1);
  return gumbel_from_bits(x0 ^ x1);
}

// ---------------------------- main kernel -----------------------------------
// Grid: ROWG * NSTRIPS blocks, 256 threads.
//   rg    = row group (128 rows rg*128 .. rg*128+127)
//   strip = column strip: chunks c with c % NSTRIPS == strip
// Per thread: 8 rows (tr + 16*i) x 8 cols (tc + 16*j) micro-tile per chunk.
// LDS tiles are XOR-swizzled ([row][d4 ^ (row&7)] in float4 units) so q-reads
// are conflict-free and e-reads are 2-way (free).
__global__ __launch_bounds__(256, 2) void advnet_main(
    const int* __restrict__ u_id, const int* __restrict__ pos_id,
    const float* __restrict__ emb, float* __restrict__ ws) {
  __shared__ float qs[128 * 64];
  __shared__ float es[128 * 64];
  float4* qs4 = (float4*)qs;
  float4* es4 = (float4*)es;

  const int tid = threadIdx.x;
  const int bid = blockIdx.x;
  const int rg = bid / NSTRIPS;
  const int strip = bid - rg * NSTRIPS;
  const int tr = tid >> 4;      // 0..15 (row team)
  const int tc = tid & 15;      // 0..15 (col team)

  // ---- stage queries: q[lr][d] = emb[u_id[b]][d] + emb[pos_id[b]][d] ----
#pragma unroll
  for (int k = 0; k < 8; ++k) {
    const int f = tid + 256 * k;         // float4 slot 0..2047
    const int lr = f >> 4, d4 = f & 15;
    const int b = rg * 128 + lr;
    const float4 a = ((const float4*)emb)[(size_t)u_id[b] * 16 + d4];
    const float4 c = ((const float4*)emb)[(size_t)pos_id[b] * 16 + d4];
    float4 q;
    q.x = a.x + c.x; q.y = a.y + c.y; q.z = a.z + c.z; q.w = a.w + c.w;
    qs4[lr * 16 + (d4 ^ (lr & 7))] = q;
  }

  // per-row-slot online state
  float m[8], Z[8], bv[8], bs[8];
  int bi[8];
#pragma unroll
  for (int i = 0; i < 8; ++i) {
    m[i] = NEG_HUGE; Z[i] = 0.0f; bv[i] = NEG_HUGE; bs[i] = 0.0f; bi[i] = 0x7fffffff;
  }

  const int qsw = tr & 7;  // (tr+16i)&7 == tr&7
  const int esw = tc & 7;

  for (int c = strip; c < NCHUNK; c += NSTRIPS) {
    const int n0 = c * CHUNK;
    __syncthreads();  // previous chunk's LDS reads done (also covers qs staging)
#pragma unroll
    for (int k = 0; k < 8; ++k) {
      const int f = tid + 256 * k;
      const int col = f >> 4, d4 = f & 15;
      const int n = n0 + col;
      float4 e = make_float4(0.f, 0.f, 0.f, 0.f);
      if (n < N_COLS) e = ((const float4*)emb)[(size_t)n * 16 + d4];
      es4[col * 16 + (d4 ^ (col & 7))] = e;
    }
    __syncthreads();

    // ---- 128x128 GEMM chunk: 8x8 per-thread register tile ----
    float acc[8][8];
#pragma unroll
    for (int i = 0; i < 8; ++i)
#pragma unroll
      for (int j = 0; j < 8; ++j) acc[i][j] = 0.0f;

#pragma unroll 4
    for (int k4 = 0; k4 < 16; ++k4) {
      float4 qv[8], ev[8];
#pragma unroll
      for (int i = 0; i < 8; ++i) qv[i] = qs4[(tr + 16 * i) * 16 + (k4 ^ qsw)];
#pragma unroll
      for (int j = 0; j < 8; ++j) ev[j] = es4[(tc + 16 * j) * 16 + (k4 ^ esw)];
#pragma unroll
      for (int i = 0; i < 8; ++i)
#pragma unroll
        for (int j = 0; j < 8; ++j) {
          acc[i][j] = fmaf(qv[i].x, ev[j].x, acc[i][j]);
          acc[i][j] = fmaf(qv[i].y, ev[j].y, acc[i][j]);
          acc[i][j] = fmaf(qv[i].z, ev[j].z, acc[i][j]);
          acc[i][j] = fmaf(qv[i].w, ev[j].w, acc[i][j]);
        }
    }

    // ---- epilogue: gumbel + online softmax + argmax over this chunk ----
#pragma unroll
    for (int j = 0; j < 8; ++j) {
      const int n = n0 + tc + 16 * j;
      if (n >= N_COLS) continue;  // only diverges in the single tail chunk
#pragma unroll
      for (int i = 0; i < 8; ++i) {
        const int brow = rg * 128 + tr + 16 * i;
        const uint32_t L = (uint32_t)brow * (uint32_t)N_COLS + (uint32_t)n;
        const float g = gumbel_at(L);
        const float s = acc[i][j];
        if (s != 0.0f) {  // s==0 -> logit -inf: no Z term, can never win
          if (s > m[i]) {
            Z[i] = Z[i] * __expf(m[i] - s) + 1.0f;
            m[i] = s;
          } else {
            Z[i] += __expf(s - m[i]);
          }
          const float v = g + s;  // gumbel + logit, f32, same as ref
          if (v > bv[i]) { bv[i] = v; bs[i] = s; bi[i] = n; }  // ascending n => first wins
        }
      }
    }
  }

  // ---- reduce across the 16-thread col-team (contiguous lanes, shfl_xor) ----
  float* wm = ws;
  float* wz = ws + (size_t)B_ROWS * NSTRIPS;
  float* wv = ws + 2 * (size_t)B_ROWS * NSTRIPS;
  float* wbs = ws + 3 * (size_t)B_ROWS * NSTRIPS;
  int* wi = (int*)(ws + 4 * (size_t)B_ROWS * NSTRIPS);

#pragma unroll
  for (int i = 0; i < 8; ++i) {
    float mi = m[i], Zi = Z[i], bvi = bv[i], bsi = bs[i];
    int bii = bi[i];
    for (int off = 1; off < 16; off <<= 1) {
      const float om = __shfl_xor(mi, off, 64);
      const float oZ = __shfl_xor(Zi, off, 64);
      const float obv = __shfl_xor(bvi, off, 64);
      const float obs = __shfl_xor(bsi, off, 64);
      const int obi = __shfl_xor(bii, off, 64);
      const float nm = fmaxf(mi, om);
      Zi = Zi * __expf(mi - nm) + oZ * __expf(om - nm);
      mi = nm;
      if (obv > bvi || (obv == bvi && obi < bii)) { bvi = obv; bsi = obs; bii = obi; }
    }
    if (tc == 0) {
      const int b = rg * 128 + tr + 16 * i;
      const size_t idx = (size_t)b * NSTRIPS + strip;
      wm[idx] = mi; wz[idx] = Zi; wv[idx] = bvi; wbs[idx] = bsi; wi[idx] = bii;
    }
  }
}

// ------------------------- cross-strip reduction ----------------------------
__global__ __launch_bounds__(128) void advnet_reduce(const float* __restrict__ ws,
                                                     float* __restrict__ out) {
  const int b = blockIdx.x;
  const int t = threadIdx.x;  // strip index 0..127
  const float* wm = ws;
  const float* wz = ws + (size_t)B_ROWS * NSTRIPS;
  const float* wv = ws + 2 * (size_t)B_ROWS * NSTRIPS;
  const float* wbs = ws + 3 * (size_t)B_ROWS * NSTRIPS;
  const int* wi = (const int*)(ws + 4 * (size_t)B_ROWS * NSTRIPS);

  const size_t idx = (size_t)b * NSTRIPS + t;
  float mi = wm[idx], Zi = wz[idx], bvi = wv[idx], bsi = wbs[idx];
  int bii = wi[idx];

  for (int off = 1; off < 64; off <<= 1) {
    const float om = __shfl_xor(mi, off, 64);
    const float oZ = __shfl_xor(Zi, off, 64);
    const float obv = __shfl_xor(bvi, off, 64);
    const float obs = __shfl_xor(bsi, off, 64);
    const int obi = __shfl_xor(bii, off, 64);
    const float nm = fmaxf(mi, om);
    Zi = Zi * __expf(mi - nm) + oZ * __expf(om - nm);
    mi = nm;
    if (obv > bvi || (obv == bvi && obi < bii)) { bvi = obv; bsi = obs; bii = obi; }
  }

  __shared__ float sm[2], sz[2], sv[2], ss_[2];
  __shared__ int si[2];
  if ((t & 63) == 0) {
    const int w = t >> 6;
    sm[w] = mi; sz[w] = Zi; sv[w] = bvi; ss_[w] = bsi; si[w] = bii;
  }
  __syncthreads();
  if (t == 0) {
    mi = sm[0]; Zi = sz[0]; bvi = sv[0]; bsi = ss_[0]; bii = si[0];
    const float m2 = sm[1], Z2 = sz[1], v2 = sv[1], s2 = ss_[1];
    const int i2 = si[1];
    const float nm = fmaxf(mi, m2);
    Zi = Zi * __expf(mi - nm) + Z2 * __expf(m2 - nm);
    mi = nm;
    if (v2 > bvi || (v2 == bvi && i2 < bii)) { bvi = v2; bsi = s2; bii = i2; }
    out[b] = (float)bii;                      // samples (int value stored as f32)
    out[B_ROWS + b] = __expf(bsi - mi) / Zi;  // selected_neg_prob
  }
}

extern "C" void kernel_launch(void* const* d_in, const int* in_sizes, int n_in,
                              void* d_out, int out_size, void* d_ws, size_t ws_size,
                              hipStream_t stream) {
  const int* u_id = (const int*)d_in[0];
  const int* pos_id = (const int*)d_in[1];
  // d_in[2] = train_mask: unused by the reference output
  const float* emb = (const float*)d_in[3];
  float* ws = (float*)d_ws;   // needs 5 * 2048 * 128 * 4B = 5.25 MB
  float* out = (float*)d_out; // [2048 samples | 2048 probs], f32

  hipLaunchKernelGGL(advnet_main, dim3(ROWG * NSTRIPS), dim3(256), 0, stream,
                     u_id, pos_id, emb, ws);
  hipLaunchKernelGGL(advnet_reduce, dim3(B_ROWS), dim3(128), 0, stream, ws, out);
}

// Round 2
// 2489.299 us; speedup vs baseline: 1.0535x; 1.0535x over previous
//
#include <hip/hip_runtime.h>
#include <stdint.h>

// Problem constants (from reference):
#define B_ROWS   2048
#define N_COLS   150000
#define NSTRIPS  128
#define CHUNK    128
#define NCHUNK   ((N_COLS + CHUNK - 1) / CHUNK)   // 1172 (last chunk has 112 cols)
#define ROWG     (B_ROWS / 128)                   // 16 row groups of 128 rows

#define NEG_HUGE (-3.0e38f)
// Gumbel hard bounds: u in [tiny, 1-2^-23] -> g in [-4.46966, +15.94238].
// Winner must satisfy s >= M - (15.94238 + 4.46966) = M - 20.41204. Margin -> 20.5.
#define G_SPAN   20.5f

// ws layout (float offsets); total ~2.93M floats = 11.8 MB
#define WS_MPART 0                                       // [B_ROWS][NSTRIPS] row-max partials
#define WS_ZPART (B_ROWS * NSTRIPS)                      // [B_ROWS][NSTRIPS] Z partials
#define WS_CMAX  (2 * B_ROWS * NSTRIPS)                  // [B_ROWS][NCHUNK] per-chunk row max
#define WS_M     (WS_CMAX + B_ROWS * NCHUNK)             // [B_ROWS]
#define WS_Z     (WS_M + B_ROWS)                         // [B_ROWS]
#define WS_TH    (WS_Z + B_ROWS)                         // [B_ROWS]

// ---------------- threefry2x32, key = (0, 42) = jax.random.key(42) ----------
// (bit-exact vs reference: verified absmax 0.0 in round 1)
__device__ __forceinline__ uint32_t rotl32(uint32_t x, int r) {
  return (x << r) | (x >> (32 - r));
}

__device__ __forceinline__ void threefry2x32_k42(uint32_t& x0, uint32_t& x1) {
  const uint32_t ks0 = 0u;
  const uint32_t ks1 = 42u;
  const uint32_t ks2 = 0x1BD11BDAu ^ 0u ^ 42u;  // 0x1BD11BF0
  x0 += ks0; x1 += ks1;
#define TF_R(r) { x0 += x1; x1 = rotl32(x1, (r)); x1 ^= x0; }
  TF_R(13) TF_R(15) TF_R(26) TF_R(6)
  x0 += ks1; x1 += ks2 + 1u;
  TF_R(17) TF_R(29) TF_R(16) TF_R(24)
  x0 += ks2; x1 += ks0 + 2u;
  TF_R(13) TF_R(15) TF_R(26) TF_R(6)
  x0 += ks0; x1 += ks1 + 3u;
  TF_R(17) TF_R(29) TF_R(16) TF_R(24)
  x0 += ks1; x1 += ks2 + 4u;
  TF_R(13) TF_R(15) TF_R(26) TF_R(6)
  x0 += ks2; x1 += ks0 + 5u;
#undef TF_R
}

__device__ __forceinline__ float gumbel_from_bits(uint32_t bits) {
  const uint32_t mant = bits >> 9;
  const float f = __uint_as_float(mant | 0x3f800000u) - 1.0f;  // exact
  const float l1 = mant ? log1pf(f - 1.0f) : -87.33654475055311f;  // ln(u)
  return -__logf(-l1);
}

__device__ __forceinline__ float gumbel_at(uint32_t flat_idx) {
  uint32_t x0 = 0u, x1 = flat_idx;
  threefry2x32_k42(x0, x1);
  return gumbel_from_bits(x0 ^ x1);
}

// order-preserving f32 -> u32; pack with complemented index so that larger
// pack == (larger v, then smaller n) -- matches first-occurrence argmax.
__device__ __forceinline__ unsigned long long pack_vn(float v, int n) {
  uint32_t u = __float_as_uint(v);
  u ^= ((uint32_t)((int32_t)u >> 31)) | 0x80000000u;
  return ((unsigned long long)u << 32) | (uint32_t)(0xFFFFFFFFu - (uint32_t)n);
}

// ------------------------------ K1: GEMM pass -------------------------------
// Per (row,strip): running row-max m and online-softmax Z; per (row,chunk):
// chunk max (for K3's candidate pruning). NO gumbel, NO argmax state here.
__global__ __launch_bounds__(256, 2) void advnet_gemm(
    const int* __restrict__ u_id, const int* __restrict__ pos_id,
    const float* __restrict__ emb, float* __restrict__ ws) {
  __shared__ float qs[128 * 64];
  __shared__ float es[128 * 64];
  float4* qs4 = (float4*)qs;
  float4* es4 = (float4*)es;

  const int tid = threadIdx.x;
  const int bid = blockIdx.x;
  const int rg = bid / NSTRIPS;
  const int strip = bid - rg * NSTRIPS;
  const int tr = tid >> 4;      // 0..15 (row team)
  const int tc = tid & 15;      // 0..15 (col team)

  // ---- stage queries: q[lr][d] = emb[u_id[b]][d] + emb[pos_id[b]][d] ----
#pragma unroll
  for (int k = 0; k < 8; ++k) {
    const int f = tid + 256 * k;         // float4 slot 0..2047
    const int lr = f >> 4, d4 = f & 15;
    const int b = rg * 128 + lr;
    const float4 a = ((const float4*)emb)[(size_t)u_id[b] * 16 + d4];
    const float4 c = ((const float4*)emb)[(size_t)pos_id[b] * 16 + d4];
    float4 q;
    q.x = a.x + c.x; q.y = a.y + c.y; q.z = a.z + c.z; q.w = a.w + c.w;
    qs4[lr * 16 + (d4 ^ (lr & 7))] = q;
  }

  float m[8], Z[8];
#pragma unroll
  for (int i = 0; i < 8; ++i) { m[i] = NEG_HUGE; Z[i] = 0.0f; }

  const int qsw = tr & 7;
  const int esw = tc & 7;

  for (int c = strip; c < NCHUNK; c += NSTRIPS) {
    const int n0 = c * CHUNK;
    __syncthreads();
#pragma unroll
    for (int k = 0; k < 8; ++k) {
      const int f = tid + 256 * k;
      const int col = f >> 4, d4 = f & 15;
      const int n = n0 + col;
      float4 e = make_float4(0.f, 0.f, 0.f, 0.f);
      if (n < N_COLS) e = ((const float4*)emb)[(size_t)n * 16 + d4];
      es4[col * 16 + (d4 ^ (col & 7))] = e;
    }
    __syncthreads();

    float acc[8][8];
#pragma unroll
    for (int i = 0; i < 8; ++i)
#pragma unroll
      for (int j = 0; j < 8; ++j) acc[i][j] = 0.0f;

#pragma unroll 4
    for (int k4 = 0; k4 < 16; ++k4) {
      float4 qv[8], ev[8];
#pragma unroll
      for (int i = 0; i < 8; ++i) qv[i] = qs4[(tr + 16 * i) * 16 + (k4 ^ qsw)];
#pragma unroll
      for (int j = 0; j < 8; ++j) ev[j] = es4[(tc + 16 * j) * 16 + (k4 ^ esw)];
#pragma unroll
      for (int i = 0; i < 8; ++i)
#pragma unroll
        for (int j = 0; j < 8; ++j) {
          acc[i][j] = fmaf(qv[i].x, ev[j].x, acc[i][j]);
          acc[i][j] = fmaf(qv[i].y, ev[j].y, acc[i][j]);
          acc[i][j] = fmaf(qv[i].z, ev[j].z, acc[i][j]);
          acc[i][j] = fmaf(qv[i].w, ev[j].w, acc[i][j]);
        }
    }

    // ---- thin epilogue: row max, online Z, chunk max. Branchless. ----
    // Padded tail cols have e==0 -> s==0 exactly -> masked (sp=NEG_HUGE),
    // same as the reference's score==0 -> -inf mask.
    float cm[8];
#pragma unroll
    for (int i = 0; i < 8; ++i) cm[i] = NEG_HUGE;
#pragma unroll
    for (int j = 0; j < 8; ++j) {
#pragma unroll
      for (int i = 0; i < 8; ++i) {
        const float s = acc[i][j];
        const float sp = (s != 0.0f) ? s : NEG_HUGE;
        cm[i] = fmaxf(cm[i], sp);
        const float nm = fmaxf(m[i], sp);
        Z[i] = Z[i] * __expf(m[i] - nm) + __expf(sp - nm);
        m[i] = nm;
      }
    }
    // reduce chunk max over the 16-lane col team, write [row][chunk]
#pragma unroll
    for (int i = 0; i < 8; ++i) {
      float v = cm[i];
      v = fmaxf(v, __shfl_xor(v, 1, 64));
      v = fmaxf(v, __shfl_xor(v, 2, 64));
      v = fmaxf(v, __shfl_xor(v, 4, 64));
      v = fmaxf(v, __shfl_xor(v, 8, 64));
      if (tc == 0) {
        const int brow = rg * 128 + tr + 16 * i;
        ws[WS_CMAX + (size_t)brow * NCHUNK + c] = v;
      }
    }
  }

  // ---- merge (m, Z) over the 16-lane col team; write per-strip partials ----
#pragma unroll
  for (int i = 0; i < 8; ++i) {
    float mi = m[i], Zi = Z[i];
    for (int off = 1; off < 16; off <<= 1) {
      const float om = __shfl_xor(mi, off, 64);
      const float oZ = __shfl_xor(Zi, off, 64);
      const float nm = fmaxf(mi, om);
      Zi = Zi * __expf(mi - nm) + oZ * __expf(om - nm);
      mi = nm;
    }
    if (tc == 0) {
      const int b = rg * 128 + tr + 16 * i;
      const size_t idx = (size_t)b * NSTRIPS + strip;
      ws[WS_MPART + idx] = mi;
      ws[WS_ZPART + idx] = Zi;
    }
  }
}

// ---------------- K2: per-row stats (M, Z, candidate threshold) -------------
__global__ __launch_bounds__(128) void advnet_rowstat(float* __restrict__ ws) {
  const int r = blockIdx.x;
  const int t = threadIdx.x;  // strip 0..127
  const size_t idx = (size_t)r * NSTRIPS + t;
  const float ms = ws[WS_MPART + idx];
  const float zs = ws[WS_ZPART + idx];

  float M = ms;
  for (int off = 1; off < 64; off <<= 1) M = fmaxf(M, __shfl_xor(M, off, 64));
  __shared__ float sM[2];
  if ((t & 63) == 0) sM[t >> 6] = M;
  __syncthreads();
  M = fmaxf(sM[0], sM[1]);

  float z = zs * __expf(ms - M);  // zs==0 for empty strips -> 0*0 = 0
  for (int off = 1; off < 64; off <<= 1) z += __shfl_xor(z, off, 64);
  __shared__ float sZ[2];
  if ((t & 63) == 0) sZ[t >> 6] = z;
  __syncthreads();
  if (t == 0) {
    ws[WS_M + r] = M;
    ws[WS_Z + r] = sZ[0] + sZ[1];
    ws[WS_TH + r] = M - G_SPAN;
  }
}

// --------- K3: candidate chunks -> exact gumbel argmax + final output -------
// One block per row. Recomputes the few surviving dot products in the exact
// same fmaf chain order as K1 (bitwise-identical s), then exact threefry
// gumbel only for s >= thresh.
__global__ __launch_bounds__(256) void advnet_pick(
    const int* __restrict__ u_id, const int* __restrict__ pos_id,
    const float* __restrict__ emb, const float* __restrict__ ws,
    float* __restrict__ out) {
  const int r = blockIdx.x;
  const int tid = threadIdx.x;

  __shared__ float qrow[64];
  __shared__ int lq[NCHUNK];
  __shared__ int lqn;
  __shared__ unsigned long long best;
  __shared__ float s_win;
  if (tid == 0) { lqn = 0; best = 0ull; s_win = 0.0f; }
  if (tid < 16) {
    const float4 a = ((const float4*)emb)[(size_t)u_id[r] * 16 + tid];
    const float4 c = ((const float4*)emb)[(size_t)pos_id[r] * 16 + tid];
    ((float4*)qrow)[tid] = make_float4(a.x + c.x, a.y + c.y, a.z + c.z, a.w + c.w);
  }
  const float M = ws[WS_M + r];
  const float Zr = ws[WS_Z + r];
  const float th = ws[WS_TH + r];
  __syncthreads();

  // queue chunks that can possibly contain the winner
  for (int c = tid; c < NCHUNK; c += 256) {
    if (ws[WS_CMAX + (size_t)r * NCHUNK + c] >= th) {
      const int k = atomicAdd(&lqn, 1);
      lq[k] = c;
    }
  }
  __syncthreads();
  const int nq = lqn;

  unsigned long long bp = 0ull;
  float bs = 0.0f;
  for (int qi = 0; qi < nq; ++qi) {
    const int c = lq[qi];
    if (tid < 128) {
      const int n = c * CHUNK + tid;
      if (n < N_COLS) {
        float s = 0.0f;
        const float4* e4 = (const float4*)emb + (size_t)n * 16;
#pragma unroll
        for (int k4 = 0; k4 < 16; ++k4) {
          const float4 e = e4[k4];
          const float4 q = ((const float4*)qrow)[k4];
          s = fmaf(q.x, e.x, s);
          s = fmaf(q.y, e.y, s);
          s = fmaf(q.z, e.z, s);
          s = fmaf(q.w, e.w, s);
        }
        if (s != 0.0f && s >= th) {
          const uint32_t L = (uint32_t)r * (uint32_t)N_COLS + (uint32_t)n;
          const float g = gumbel_at(L);
          const float v = g + s;
          const unsigned long long p = pack_vn(v, n);
          if (p > bp) { bp = p; bs = s; }
        }
      }
    }
  }
  if (bp) atomicMax(&best, bp);
  __syncthreads();
  if (bp && bp == best) s_win = bs;  // unique winner element -> unique writer
  __syncthreads();
  if (tid == 0) {
    const unsigned long long w = best;
    const int n_win = (int)(0xFFFFFFFFu - (uint32_t)(w & 0xFFFFFFFFull));
    out[r] = (float)n_win;
    out[B_ROWS + r] = __expf(s_win - M) / Zr;
  }
}

extern "C" void kernel_launch(void* const* d_in, const int* in_sizes, int n_in,
                              void* d_out, int out_size, void* d_ws, size_t ws_size,
                              hipStream_t stream) {
  const int* u_id = (const int*)d_in[0];
  const int* pos_id = (const int*)d_in[1];
  // d_in[2] = train_mask: unused by the reference output
  const float* emb = (const float*)d_in[3];
  float* ws = (float*)d_ws;   // needs (2*2048*128 + 2048*1172 + 3*2048)*4 = 11.8 MB
  float* out = (float*)d_out; // [2048 samples | 2048 probs], f32

  hipLaunchKernelGGL(advnet_gemm, dim3(ROWG * NSTRIPS), dim3(256), 0, stream,
                     u_id, pos_id, emb, ws);
  hipLaunchKernelGGL(advnet_rowstat, dim3(B_ROWS), dim3(128), 0, stream, ws);
  hipLaunchKernelGGL(advnet_pick, dim3(B_ROWS), dim3(256), 0, stream,
                     u_id, pos_id, emb, ws, out);
}

// Round 3
// 1014.411 us; speedup vs baseline: 2.5853x; 2.4539x over previous
//
#include <hip/hip_runtime.h>
#include <stdint.h>

// Problem constants (from reference):
#define B_ROWS   2048
#define N_COLS   150000
#define NSTRIPS  128
#define CHUNK    128
#define NCHUNK   ((N_COLS + CHUNK - 1) / CHUNK)   // 1172 (last chunk has 112 cols)
#define ROWG     (B_ROWS / 128)                   // 16 row groups of 128 rows
#define SSTRIDE  16                               // chunk-scan stripes per row (K3)

#define NEG_HUGE (-3.0e38f)
// Gumbel hard bounds: u in [tiny, 1-2^-23] -> g in [-4.46966, +15.94238].
// Hard winner bound: s >= M - 20.412 (margin -> 20.5).
#define G_SPAN_HARD  20.5f
// Tight bound once a certified winner lower-bound v_lb exists:
// winner needs s >= v_lb - g_max  (g_max = 15.94238 + __logf err; margin -> 15.944)
#define G_MAX_MARGIN 15.944f

// ws layout (float offsets); total 2,936,832 floats = 11.2 MiB
#define WS_MPART 0                                       // [B_ROWS][NSTRIPS] row-max partials
#define WS_ZPART (B_ROWS * NSTRIPS)                      // [B_ROWS][NSTRIPS] Z partials
#define WS_CMAX  (2 * B_ROWS * NSTRIPS)                  // [B_ROWS][NCHUNK] per-chunk row max
#define WS_M     (WS_CMAX + B_ROWS * NCHUNK)             // [B_ROWS] row max
#define WS_Z     (WS_M + B_ROWS)                         // [B_ROWS] softmax denom
#define WS_TH    (WS_Z + B_ROWS)                         // [B_ROWS] tight threshold
#define WS_CSTAR (WS_TH + B_ROWS)                        // [B_ROWS] argmax chunk (int)
#define WS_BEST  (WS_CSTAR + B_ROWS)                     // [B_ROWS] u64 packed best (8B aligned)

// ---------------- threefry2x32, key = (0, 42) = jax.random.key(42) ----------
// (bit-exact vs reference: verified absmax 0.0 in rounds 1-2)
__device__ __forceinline__ uint32_t rotl32(uint32_t x, int r) {
  return (x << r) | (x >> (32 - r));
}

__device__ __forceinline__ void threefry2x32_k42(uint32_t& x0, uint32_t& x1) {
  const uint32_t ks0 = 0u;
  const uint32_t ks1 = 42u;
  const uint32_t ks2 = 0x1BD11BDAu ^ 0u ^ 42u;  // 0x1BD11BF0
  x0 += ks0; x1 += ks1;
#define TF_R(r) { x0 += x1; x1 = rotl32(x1, (r)); x1 ^= x0; }
  TF_R(13) TF_R(15) TF_R(26) TF_R(6)
  x0 += ks1; x1 += ks2 + 1u;
  TF_R(17) TF_R(29) TF_R(16) TF_R(24)
  x0 += ks2; x1 += ks0 + 2u;
  TF_R(13) TF_R(15) TF_R(26) TF_R(6)
  x0 += ks0; x1 += ks1 + 3u;
  TF_R(17) TF_R(29) TF_R(16) TF_R(24)
  x0 += ks1; x1 += ks2 + 4u;
  TF_R(13) TF_R(15) TF_R(26) TF_R(6)
  x0 += ks2; x1 += ks0 + 5u;
#undef TF_R
}

__device__ __forceinline__ float gumbel_from_bits(uint32_t bits) {
  const uint32_t mant = bits >> 9;
  const float f = __uint_as_float(mant | 0x3f800000u) - 1.0f;  // exact
  const float l1 = mant ? log1pf(f - 1.0f) : -87.33654475055311f;  // ln(u)
  return -__logf(-l1);
}

__device__ __forceinline__ float gumbel_at(uint32_t flat_idx) {
  uint32_t x0 = 0u, x1 = flat_idx;
  threefry2x32_k42(x0, x1);
  return gumbel_from_bits(x0 ^ x1);
}

// order-preserving f32 -> u32; pack with complemented index so that larger
// pack == (larger v, then smaller n) -- matches first-occurrence argmax.
__device__ __forceinline__ unsigned long long pack_vn(float v, int n) {
  uint32_t u = __float_as_uint(v);
  u ^= ((uint32_t)((int32_t)u >> 31)) | 0x80000000u;
  return ((unsigned long long)u << 32) | (uint32_t)(0xFFFFFFFFu - (uint32_t)n);
}

__device__ __forceinline__ float unpack_v(unsigned long long p) {
  uint32_t u = (uint32_t)(p >> 32);
  u = (u & 0x80000000u) ? (u ^ 0x80000000u) : ~u;
  return __uint_as_float(u);
}

__device__ __forceinline__ int unpack_n(unsigned long long p) {
  return (int)(0xFFFFFFFFu - (uint32_t)(p & 0xFFFFFFFFull));
}

__device__ __forceinline__ unsigned long long umax64(unsigned long long a,
                                                     unsigned long long b) {
  return a > b ? a : b;
}

// The canonical dot: MUST match K1's fmaf chain bitwise (k4 ascending, xyzw).
__device__ __forceinline__ float dot_q_e(const float4* q4, const float4* e4) {
  float s = 0.0f;
#pragma unroll
  for (int k4 = 0; k4 < 16; ++k4) {
    const float4 e = e4[k4];
    const float4 q = q4[k4];
    s = fmaf(q.x, e.x, s);
    s = fmaf(q.y, e.y, s);
    s = fmaf(q.z, e.z, s);
    s = fmaf(q.w, e.w, s);
  }
  return s;
}

// ------------------------------ K1: GEMM pass -------------------------------
// Per (row,strip): running row-max m and online-softmax Z; per (row,chunk):
// chunk max (for candidate pruning). NO gumbel, NO argmax state here.
__global__ __launch_bounds__(256, 2) void advnet_gemm(
    const int* __restrict__ u_id, const int* __restrict__ pos_id,
    const float* __restrict__ emb, float* __restrict__ ws) {
  __shared__ float qs[128 * 64];
  __shared__ float es[128 * 64];
  float4* qs4 = (float4*)qs;
  float4* es4 = (float4*)es;

  const int tid = threadIdx.x;
  const int bid = blockIdx.x;
  const int rg = bid / NSTRIPS;
  const int strip = bid - rg * NSTRIPS;
  const int tr = tid >> 4;      // 0..15 (row team)
  const int tc = tid & 15;      // 0..15 (col team)

  // ---- stage queries: q[lr][d] = emb[u_id[b]][d] + emb[pos_id[b]][d] ----
#pragma unroll
  for (int k = 0; k < 8; ++k) {
    const int f = tid + 256 * k;         // float4 slot 0..2047
    const int lr = f >> 4, d4 = f & 15;
    const int b = rg * 128 + lr;
    const float4 a = ((const float4*)emb)[(size_t)u_id[b] * 16 + d4];
    const float4 c = ((const float4*)emb)[(size_t)pos_id[b] * 16 + d4];
    float4 q;
    q.x = a.x + c.x; q.y = a.y + c.y; q.z = a.z + c.z; q.w = a.w + c.w;
    qs4[lr * 16 + (d4 ^ (lr & 7))] = q;
  }

  float m[8], Z[8];
#pragma unroll
  for (int i = 0; i < 8; ++i) { m[i] = NEG_HUGE; Z[i] = 0.0f; }

  const int qsw = tr & 7;
  const int esw = tc & 7;

  for (int c = strip; c < NCHUNK; c += NSTRIPS) {
    const int n0 = c * CHUNK;
    __syncthreads();
#pragma unroll
    for (int k = 0; k < 8; ++k) {
      const int f = tid + 256 * k;
      const int col = f >> 4, d4 = f & 15;
      const int n = n0 + col;
      float4 e = make_float4(0.f, 0.f, 0.f, 0.f);
      if (n < N_COLS) e = ((const float4*)emb)[(size_t)n * 16 + d4];
      es4[col * 16 + (d4 ^ (col & 7))] = e;
    }
    __syncthreads();

    float acc[8][8];
#pragma unroll
    for (int i = 0; i < 8; ++i)
#pragma unroll
      for (int j = 0; j < 8; ++j) acc[i][j] = 0.0f;

#pragma unroll 4
    for (int k4 = 0; k4 < 16; ++k4) {
      float4 qv[8], ev[8];
#pragma unroll
      for (int i = 0; i < 8; ++i) qv[i] = qs4[(tr + 16 * i) * 16 + (k4 ^ qsw)];
#pragma unroll
      for (int j = 0; j < 8; ++j) ev[j] = es4[(tc + 16 * j) * 16 + (k4 ^ esw)];
#pragma unroll
      for (int i = 0; i < 8; ++i)
#pragma unroll
        for (int j = 0; j < 8; ++j) {
          acc[i][j] = fmaf(qv[i].x, ev[j].x, acc[i][j]);
          acc[i][j] = fmaf(qv[i].y, ev[j].y, acc[i][j]);
          acc[i][j] = fmaf(qv[i].z, ev[j].z, acc[i][j]);
          acc[i][j] = fmaf(qv[i].w, ev[j].w, acc[i][j]);
        }
    }

    // ---- thin epilogue: row max, online Z, chunk max. Branchless. ----
    float cm[8];
#pragma unroll
    for (int i = 0; i < 8; ++i) cm[i] = NEG_HUGE;
#pragma unroll
    for (int j = 0; j < 8; ++j) {
#pragma unroll
      for (int i = 0; i < 8; ++i) {
        const float s = acc[i][j];
        const float sp = (s != 0.0f) ? s : NEG_HUGE;
        cm[i] = fmaxf(cm[i], sp);
        const float nm = fmaxf(m[i], sp);
        Z[i] = Z[i] * __expf(m[i] - nm) + __expf(sp - nm);
        m[i] = nm;
      }
    }
#pragma unroll
    for (int i = 0; i < 8; ++i) {
      float v = cm[i];
      v = fmaxf(v, __shfl_xor(v, 1, 64));
      v = fmaxf(v, __shfl_xor(v, 2, 64));
      v = fmaxf(v, __shfl_xor(v, 4, 64));
      v = fmaxf(v, __shfl_xor(v, 8, 64));
      if (tc == 0) {
        const int brow = rg * 128 + tr + 16 * i;
        ws[WS_CMAX + (size_t)brow * NCHUNK + c] = v;
      }
    }
  }

#pragma unroll
  for (int i = 0; i < 8; ++i) {
    float mi = m[i], Zi = Z[i];
    for (int off = 1; off < 16; off <<= 1) {
      const float om = __shfl_xor(mi, off, 64);
      const float oZ = __shfl_xor(Zi, off, 64);
      const float nm = fmaxf(mi, om);
      Zi = Zi * __expf(mi - nm) + oZ * __expf(om - nm);
      mi = nm;
    }
    if (tc == 0) {
      const int b = rg * 128 + tr + 16 * i;
      const size_t idx = (size_t)b * NSTRIPS + strip;
      ws[WS_MPART + idx] = mi;
      ws[WS_ZPART + idx] = Zi;
    }
  }
}

// ------- K2: per-row stats + seed winner from argmax chunk (tight th) -------
// One block (128 threads) per row.
__global__ __launch_bounds__(128) void advnet_rowstat(
    const int* __restrict__ u_id, const int* __restrict__ pos_id,
    const float* __restrict__ emb, float* __restrict__ ws) {
  const int r = blockIdx.x;
  const int t = threadIdx.x;  // 0..127

  __shared__ float sA[2], sB[2];
  __shared__ unsigned long long sP[2];
  __shared__ float qrow[64];

  // ---- M, Z over 128 strip partials ----
  const size_t idx = (size_t)r * NSTRIPS + t;
  const float ms = ws[WS_MPART + idx];
  const float zs = ws[WS_ZPART + idx];
  float M = ms;
  for (int off = 1; off < 64; off <<= 1) M = fmaxf(M, __shfl_xor(M, off, 64));
  if ((t & 63) == 0) sA[t >> 6] = M;
  __syncthreads();
  M = fmaxf(sA[0], sA[1]);
  float z = zs * __expf(ms - M);  // zs==0 for empty strips -> 0
  for (int off = 1; off < 64; off <<= 1) z += __shfl_xor(z, off, 64);
  if ((t & 63) == 0) sB[t >> 6] = z;
  __syncthreads();
  const float Z = sB[0] + sB[1];

  // ---- find c* = chunk containing the row max (smallest on ties) ----
  unsigned long long cp = 0ull;
  for (int c = t; c < NCHUNK; c += 128)
    cp = umax64(cp, pack_vn(ws[WS_CMAX + (size_t)r * NCHUNK + c], c));
  for (int off = 1; off < 64; off <<= 1)
    cp = umax64(cp, __shfl_xor(cp, off, 64));
  if ((t & 63) == 0) sP[t >> 6] = cp;
  __syncthreads();
  cp = umax64(sP[0], sP[1]);
  const int cstar = unpack_n(cp);

  // ---- stage q row ----
  if (t < 16) {
    const float4 a = ((const float4*)emb)[(size_t)u_id[r] * 16 + t];
    const float4 c = ((const float4*)emb)[(size_t)pos_id[r] * 16 + t];
    ((float4*)qrow)[t] = make_float4(a.x + c.x, a.y + c.y, a.z + c.z, a.w + c.w);
  }
  __syncthreads();  // also separates sP read above from reuse below

  // ---- fully evaluate chunk c* under the HARD bound -> certified v_lb ----
  unsigned long long bp = 0ull;
  const int n = cstar * CHUNK + t;
  if (n < N_COLS) {
    const float s = dot_q_e((const float4*)qrow, (const float4*)emb + (size_t)n * 16);
    if (s != 0.0f && s >= M - G_SPAN_HARD) {
      const uint32_t L = (uint32_t)r * (uint32_t)N_COLS + (uint32_t)n;
      bp = pack_vn(gumbel_at(L) + s, n);
    }
  }
  for (int off = 1; off < 64; off <<= 1)
    bp = umax64(bp, __shfl_xor(bp, off, 64));
  if ((t & 63) == 0) sP[t >> 6] = bp;
  __syncthreads();
  if (t == 0) {
    const unsigned long long best = umax64(sP[0], sP[1]);
    ((unsigned long long*)(ws + WS_BEST))[r] = best;   // seed (plain store: resets each call)
    ws[WS_TH + r] = unpack_v(best) - G_MAX_MARGIN;     // tight, still exact
    ws[WS_M + r] = M;
    ws[WS_Z + r] = Z;
    ((int*)ws)[WS_CSTAR + r] = cstar;
  }
}

// ---- K3: scan candidate chunks (16 stripes/row), exact gumbel on survivors --
__global__ __launch_bounds__(128) void advnet_scan(
    const int* __restrict__ u_id, const int* __restrict__ pos_id,
    const float* __restrict__ emb, float* __restrict__ ws) {
  const int bid = blockIdx.x;
  const int r = bid >> 4;          // row
  const int stripe = bid & 15;     // chunk stripe
  const int t = threadIdx.x;       // 0..127 = col within chunk

  __shared__ float qrow[64];
  if (t < 16) {
    const float4 a = ((const float4*)emb)[(size_t)u_id[r] * 16 + t];
    const float4 c = ((const float4*)emb)[(size_t)pos_id[r] * 16 + t];
    ((float4*)qrow)[t] = make_float4(a.x + c.x, a.y + c.y, a.z + c.z, a.w + c.w);
  }
  const float th = ws[WS_TH + r];
  const int cstar = ((const int*)ws)[WS_CSTAR + r];
  __syncthreads();

  unsigned long long bp = 0ull;
  for (int c = stripe; c < NCHUNK; c += SSTRIDE) {
    if (c == cstar) continue;  // fully covered by K2's seed
    const float cmv = ws[WS_CMAX + (size_t)r * NCHUNK + c];  // wave-uniform
    if (cmv < th) continue;
    const int n = c * CHUNK + t;
    if (n < N_COLS) {
      const float s = dot_q_e((const float4*)qrow, (const float4*)emb + (size_t)n * 16);
      if (s != 0.0f && s >= th) {
        const uint32_t L = (uint32_t)r * (uint32_t)N_COLS + (uint32_t)n;
        bp = umax64(bp, pack_vn(gumbel_at(L) + s, n));
      }
    }
  }
  if (bp)
    atomicMax((unsigned long long*)(ws + WS_BEST) + r, bp);
}

// --------------------------- K4: finalize outputs ---------------------------
__global__ __launch_bounds__(64) void advnet_final(
    const int* __restrict__ u_id, const int* __restrict__ pos_id,
    const float* __restrict__ emb, const float* __restrict__ ws,
    float* __restrict__ out) {
  const int r = blockIdx.x * 64 + threadIdx.x;
  if (r >= B_ROWS) return;
  const unsigned long long w = ((const unsigned long long*)(ws + WS_BEST))[r];
  const int n = unpack_n(w);
  // recompute winner's score exactly (identical fmaf chain)
  const float4* qa = (const float4*)emb + (size_t)u_id[r] * 16;
  const float4* qb = (const float4*)emb + (size_t)pos_id[r] * 16;
  const float4* e4 = (const float4*)emb + (size_t)n * 16;
  float s = 0.0f;
#pragma unroll
  for (int k4 = 0; k4 < 16; ++k4) {
    const float4 a = qa[k4], b = qb[k4], e = e4[k4];
    float4 q;
    q.x = a.x + b.x; q.y = a.y + b.y; q.z = a.z + b.z; q.w = a.w + b.w;
    s = fmaf(q.x, e.x, s);
    s = fmaf(q.y, e.y, s);
    s = fmaf(q.z, e.z, s);
    s = fmaf(q.w, e.w, s);
  }
  out[r] = (float)n;
  out[B_ROWS + r] = __expf(s - ws[WS_M + r]) / ws[WS_Z + r];
}

extern "C" void kernel_launch(void* const* d_in, const int* in_sizes, int n_in,
                              void* d_out, int out_size, void* d_ws, size_t ws_size,
                              hipStream_t stream) {
  const int* u_id = (const int*)d_in[0];
  const int* pos_id = (const int*)d_in[1];
  // d_in[2] = train_mask: unused by the reference output
  const float* emb = (const float*)d_in[3];
  float* ws = (float*)d_ws;   // 11.2 MiB used
  float* out = (float*)d_out; // [2048 samples | 2048 probs], f32

  hipLaunchKernelGGL(advnet_gemm, dim3(ROWG * NSTRIPS), dim3(256), 0, stream,
                     u_id, pos_id, emb, ws);
  hipLaunchKernelGGL(advnet_rowstat, dim3(B_ROWS), dim3(128), 0, stream,
                     u_id, pos_id, emb, ws);
  hipLaunchKernelGGL(advnet_scan, dim3(B_ROWS * SSTRIDE), dim3(128), 0, stream,
                     u_id, pos_id, emb, ws);
  hipLaunchKernelGGL(advnet_final, dim3(B_ROWS / 64), dim3(64), 0, stream,
                     u_id, pos_id, emb, ws, out);
}

// Round 4
// 651.267 us; speedup vs baseline: 4.0268x; 1.5576x over previous
//
#include <hip/hip_runtime.h>
#include <stdint.h>

// Problem constants (from reference):
#define B_ROWS   2048
#define N_COLS   150000
#define NSTRIPS  128
#define CHUNK    128
#define NCHUNK   1172                             // ceil(150000/128), tail has 112 cols
#define ROWG     16                               // 2048/128 row groups
#define SSTRIDE  16                               // chunk-scan stripes per row (K3)

#define NEG_HUGE (-3.0e38f)
// Gumbel hard bounds: u in [tiny, 1-2^-23] -> g in [-4.46966, +15.94238].
// Hard winner bound: s >= M - 20.412 - 2B (B = mfma split bound, <=0.04) -> 20.6.
#define G_SPAN_HARD  20.6f
// Tight bound once a certified winner lower-bound v_lb exists:
#define G_MAX_MARGIN 15.944f
// Certified |s_canon - s_mfma| <= ||q||2 * ||e||2 * EPS_B  (split 2^-15 + accum; 2.8x margin)
#define EPS_B        2.0e-4f

// ws layout (float offsets); total 2,940,928 floats = 11.8 MiB
#define WS_MPART 0                                       // [B_ROWS][NSTRIPS]
#define WS_ZPART (B_ROWS * NSTRIPS)                      // [B_ROWS][NSTRIPS]
#define WS_CMAX  (2 * B_ROWS * NSTRIPS)                  // [B_ROWS][NCHUNK] mfma chunk max
#define WS_M     (WS_CMAX + B_ROWS * NCHUNK)             // [B_ROWS] anchor max
#define WS_Z     (WS_M + B_ROWS)                         // [B_ROWS] softmax denom
#define WS_TH    (WS_Z + B_ROWS)                         // [B_ROWS] tight threshold
#define WS_CSTAR (WS_TH + B_ROWS)                        // [B_ROWS] argmax chunk (int)
#define WS_BEST  (WS_CSTAR + B_ROWS)                     // [B_ROWS] u64 packed best
#define WS_ENORM (WS_BEST + 2 * B_ROWS)                  // [NCHUNK->2048] chunk max ||e||
#define WS_QNORM (WS_ENORM + 2048)                       // [B_ROWS] row ||q||

typedef __attribute__((ext_vector_type(8))) unsigned short ushort8;
typedef __attribute__((ext_vector_type(8))) short short8;
typedef __attribute__((ext_vector_type(4))) float f32x4;

// ---------------- threefry2x32, key = (0, 42) = jax.random.key(42) ----------
// (bit-exact vs reference: verified absmax 0.0 in rounds 1-3)
__device__ __forceinline__ uint32_t rotl32(uint32_t x, int r) {
  return (x << r) | (x >> (32 - r));
}

__device__ __forceinline__ void threefry2x32_k42(uint32_t& x0, uint32_t& x1) {
  const uint32_t ks0 = 0u;
  const uint32_t ks1 = 42u;
  const uint32_t ks2 = 0x1BD11BDAu ^ 0u ^ 42u;
  x0 += ks0; x1 += ks1;
#define TF_R(r) { x0 += x1; x1 = rotl32(x1, (r)); x1 ^= x0; }
  TF_R(13) TF_R(15) TF_R(26) TF_R(6)
  x0 += ks1; x1 += ks2 + 1u;
  TF_R(17) TF_R(29) TF_R(16) TF_R(24)
  x0 += ks2; x1 += ks0 + 2u;
  TF_R(13) TF_R(15) TF_R(26) TF_R(6)
  x0 += ks0; x1 += ks1 + 3u;
  TF_R(17) TF_R(29) TF_R(16) TF_R(24)
  x0 += ks1; x1 += ks2 + 4u;
  TF_R(13) TF_R(15) TF_R(26) TF_R(6)
  x0 += ks2; x1 += ks0 + 5u;
#undef TF_R
}

__device__ __forceinline__ float gumbel_from_bits(uint32_t bits) {
  const uint32_t mant = bits >> 9;
  const float f = __uint_as_float(mant | 0x3f800000u) - 1.0f;  // exact
  const float l1 = mant ? log1pf(f - 1.0f) : -87.33654475055311f;  // ln(u)
  return -__logf(-l1);
}

__device__ __forceinline__ float gumbel_at(uint32_t flat_idx) {
  uint32_t x0 = 0u, x1 = flat_idx;
  threefry2x32_k42(x0, x1);
  return gumbel_from_bits(x0 ^ x1);
}

// order-preserving f32 pack with complemented index (first-occurrence argmax).
__device__ __forceinline__ unsigned long long pack_vn(float v, int n) {
  uint32_t u = __float_as_uint(v);
  u ^= ((uint32_t)((int32_t)u >> 31)) | 0x80000000u;
  return ((unsigned long long)u << 32) | (uint32_t)(0xFFFFFFFFu - (uint32_t)n);
}

__device__ __forceinline__ float unpack_v(unsigned long long p) {
  uint32_t u = (uint32_t)(p >> 32);
  u = (u & 0x80000000u) ? (u ^ 0x80000000u) : ~u;
  return __uint_as_float(u);
}

__device__ __forceinline__ int unpack_n(unsigned long long p) {
  return (int)(0xFFFFFFFFu - (uint32_t)(p & 0xFFFFFFFFull));
}

__device__ __forceinline__ unsigned long long umax64(unsigned long long a,
                                                     unsigned long long b) {
  return a > b ? a : b;
}

// Canonical f32 dot: all exact-path evaluations use THIS chain (consistent).
__device__ __forceinline__ float dot_q_e(const float4* q4, const float4* e4) {
  float s = 0.0f;
#pragma unroll
  for (int k4 = 0; k4 < 16; ++k4) {
    const float4 e = e4[k4];
    const float4 q = q4[k4];
    s = fmaf(q.x, e.x, s);
    s = fmaf(q.y, e.y, s);
    s = fmaf(q.z, e.z, s);
    s = fmaf(q.w, e.w, s);
  }
  return s;
}

// bf16 split helpers (explicit RNE)
__device__ __forceinline__ unsigned short f32_to_bf16_rne(float f) {
  const uint32_t u = __float_as_uint(f);
  return (unsigned short)((u + 0x7fffu + ((u >> 16) & 1u)) >> 16);
}
__device__ __forceinline__ float bf16_to_f32(unsigned short h) {
  return __uint_as_float(((uint32_t)h) << 16);
}

// ---------------- K0: per-chunk max ||e||_2 (for certified bound B) --------
__global__ __launch_bounds__(256) void advnet_enorm(const float* __restrict__ emb,
                                                    float* __restrict__ ws) {
  const int c = blockIdx.x;
  const int t = threadIdx.x;
  const int lane = t & 63;
  const int row = t >> 1;
  const int n = c * CHUNK + row;
  float ss = 0.0f;
  if (n < N_COLS) {
    const float4* p = (const float4*)emb + (size_t)n * 16 + (t & 1) * 8;
#pragma unroll
    for (int i = 0; i < 8; ++i) {
      const float4 v = p[i];
      ss = fmaf(v.x, v.x, ss); ss = fmaf(v.y, v.y, ss);
      ss = fmaf(v.z, v.z, ss); ss = fmaf(v.w, v.w, ss);
    }
  }
  ss += __shfl_xor(ss, 1, 64);
  float mx = ss;
  for (int off = 2; off < 64; off <<= 1) mx = fmaxf(mx, __shfl_xor(mx, off, 64));
  __shared__ float sm[4];
  if (lane == 0) sm[t >> 6] = mx;
  __syncthreads();
  if (t == 0)
    ws[WS_ENORM + c] =
        sqrtf(fmaxf(fmaxf(sm[0], sm[1]), fmaxf(sm[2], sm[3]))) * 1.00002f;
}

// ------------------------- K1: MFMA GEMM pass -------------------------------
// 2048 blocks (16 rowgroups x 128 strips), 256 thr = 4 waves.
// Per chunk: stage e as bf16 hi/lo in LDS (XOR-swizzled 16B granules), then
// s ~= qh*eh + qh*el + ql*eh via mfma_f32_16x16x32_bf16 (6 MFMA / 16x16 tile).
// Wave w owns rows w*32..w*32+31 x all 128 cols. Outputs: per-(row,strip)
// online (m,Z) partials + per-(row,chunk) mfma max.
__global__ __launch_bounds__(256, 2) void advnet_gemm(
    const int* __restrict__ u_id, const int* __restrict__ pos_id,
    const float* __restrict__ emb, float* __restrict__ ws) {
  __shared__ unsigned short qh_s[128 * 64];
  __shared__ unsigned short ql_s[128 * 64];
  __shared__ unsigned short eh_s[128 * 64];
  __shared__ unsigned short el_s[128 * 64];

  const int tid = threadIdx.x;
  const int bid = blockIdx.x;
  const int rg = bid / NSTRIPS;
  const int strip = bid - rg * NSTRIPS;
  const int wave = tid >> 6;
  const int lane = tid & 63;
  const int lc = lane & 15;   // A-row / B-col within 16-tile
  const int lg = lane >> 4;   // k-granule selector (0..3)

  // ---- stage q split: q = emb[u]+emb[pos] (f32) -> bf16 hi/lo, swizzled ----
#pragma unroll
  for (int k = 0; k < 4; ++k) {
    const int p = tid + 256 * k;        // half-row granule pair 0..1023
    const int row = p >> 3, kq = p & 7;
    const int b = rg * 128 + row;
    const float4* ua = (const float4*)emb + (size_t)u_id[b] * 16 + kq * 2;
    const float4* pa = (const float4*)emb + (size_t)pos_id[b] * 16 + kq * 2;
    const float4 a0 = ua[0], a1 = ua[1], c0 = pa[0], c1 = pa[1];
    const float q[8] = {a0.x + c0.x, a0.y + c0.y, a0.z + c0.z, a0.w + c0.w,
                        a1.x + c1.x, a1.y + c1.y, a1.z + c1.z, a1.w + c1.w};
    ushort8 hi, lo;
#pragma unroll
    for (int j = 0; j < 8; ++j) {
      const unsigned short h = f32_to_bf16_rne(q[j]);
      hi[j] = h;
      lo[j] = f32_to_bf16_rne(q[j] - bf16_to_f32(h));
    }
    const int off = row * 64 + ((kq * 8) ^ ((row & 7) << 3));  // ushort units
    *(ushort8*)&qh_s[off] = hi;
    *(ushort8*)&ql_s[off] = lo;
  }

  float m[8], Z[8];
#pragma unroll
  for (int s = 0; s < 8; ++s) { m[s] = NEG_HUGE; Z[s] = 0.0f; }

  for (int c = strip; c < NCHUNK; c += NSTRIPS) {
    const int n0 = c * CHUNK;
    __syncthreads();  // previous chunk's LDS reads done (also covers q staging)
    // ---- stage e chunk: f32 -> bf16 hi/lo in LDS ----
#pragma unroll
    for (int k = 0; k < 4; ++k) {
      const int p = tid + 256 * k;
      const int row = p >> 3, kq = p & 7;
      const int n = n0 + row;
      ushort8 hi = (ushort8)0, lo = (ushort8)0;
      if (n < N_COLS) {
        const float4* ep = (const float4*)emb + (size_t)n * 16 + kq * 2;
        const float4 a0 = ep[0], a1 = ep[1];
        const float e[8] = {a0.x, a0.y, a0.z, a0.w, a1.x, a1.y, a1.z, a1.w};
#pragma unroll
        for (int j = 0; j < 8; ++j) {
          const unsigned short h = f32_to_bf16_rne(e[j]);
          hi[j] = h;
          lo[j] = f32_to_bf16_rne(e[j] - bf16_to_f32(h));
        }
      }
      const int off = row * 64 + ((kq * 8) ^ ((row & 7) << 3));
      *(ushort8*)&eh_s[off] = hi;
      *(ushort8*)&el_s[off] = lo;
    }
    __syncthreads();

    // ---- MFMA: acc = qh*eh + qh*el + ql*eh over K=64 (2 k-halves) ----
    f32x4 acc[2][8];
#pragma unroll
    for (int rt = 0; rt < 2; ++rt)
#pragma unroll
      for (int ct = 0; ct < 8; ++ct) acc[rt][ct] = (f32x4){0.f, 0.f, 0.f, 0.f};

#pragma unroll
    for (int kh = 0; kh < 2; ++kh) {
      short8 qhf[2], qlf[2];
#pragma unroll
      for (int rt = 0; rt < 2; ++rt) {
        const int r = wave * 32 + rt * 16 + lc;
        const int off = r * 64 + (((kh * 4 + lg) * 8) ^ ((r & 7) << 3));
        qhf[rt] = *(const short8*)&qh_s[off];
        qlf[rt] = *(const short8*)&ql_s[off];
      }
#pragma unroll
      for (int ct = 0; ct < 8; ++ct) {
        const int col = ct * 16 + lc;
        const int off = col * 64 + (((kh * 4 + lg) * 8) ^ ((col & 7) << 3));
        const short8 ehf = *(const short8*)&eh_s[off];
        const short8 elf = *(const short8*)&el_s[off];
#pragma unroll
        for (int rt = 0; rt < 2; ++rt) {
          acc[rt][ct] = __builtin_amdgcn_mfma_f32_16x16x32_bf16(qhf[rt], ehf, acc[rt][ct], 0, 0, 0);
          acc[rt][ct] = __builtin_amdgcn_mfma_f32_16x16x32_bf16(qhf[rt], elf, acc[rt][ct], 0, 0, 0);
          acc[rt][ct] = __builtin_amdgcn_mfma_f32_16x16x32_bf16(qlf[rt], ehf, acc[rt][ct], 0, 0, 0);
        }
      }
    }

    // ---- epilogue: per-lane 8 row-slots x 8 cols: online (m,Z) + chunk max --
    // C layout (m89): col = lane&15, row = (lane>>4)*4 + reg.
#pragma unroll
    for (int rt = 0; rt < 2; ++rt) {
#pragma unroll
      for (int j = 0; j < 4; ++j) {
        const int s = rt * 4 + j;
        float sp[8];
        float cm = NEG_HUGE;
#pragma unroll
        for (int ct = 0; ct < 8; ++ct) {
          const float v = acc[rt][ct][j];
          sp[ct] = (v != 0.0f) ? v : NEG_HUGE;  // score==0 -> -inf mask
          cm = fmaxf(cm, sp[ct]);
        }
        const float nm = fmaxf(m[s], cm);
        float za = 0.0f;
#pragma unroll
        for (int ct = 0; ct < 8; ++ct) za += __expf(sp[ct] - nm);
        Z[s] = Z[s] * __expf(m[s] - nm) + za;
        m[s] = nm;
        float cr = cm;
        cr = fmaxf(cr, __shfl_xor(cr, 1, 64));
        cr = fmaxf(cr, __shfl_xor(cr, 2, 64));
        cr = fmaxf(cr, __shfl_xor(cr, 4, 64));
        cr = fmaxf(cr, __shfl_xor(cr, 8, 64));
        if (lc == 0) {
          const int row = rg * 128 + wave * 32 + rt * 16 + lg * 4 + j;
          ws[WS_CMAX + (size_t)row * NCHUNK + c] = cr;
        }
      }
    }
  }

  // ---- merge (m,Z) over the 16 lanes sharing each row; write partials ----
#pragma unroll
  for (int rt = 0; rt < 2; ++rt) {
#pragma unroll
    for (int j = 0; j < 4; ++j) {
      const int s = rt * 4 + j;
      float mi = m[s], Zi = Z[s];
      for (int off = 1; off < 16; off <<= 1) {
        const float om = __shfl_xor(mi, off, 64);
        const float oZ = __shfl_xor(Zi, off, 64);
        const float nm = fmaxf(mi, om);
        Zi = Zi * __expf(mi - nm) + oZ * __expf(om - nm);
        mi = nm;
      }
      if (lc == 0) {
        const int row = rg * 128 + wave * 32 + rt * 16 + lg * 4 + j;
        ws[WS_MPART + (size_t)row * NSTRIPS + strip] = mi;
        ws[WS_ZPART + (size_t)row * NSTRIPS + strip] = Zi;
      }
    }
  }
}

// ------- K2: per-row stats + seed winner from argmax chunk (tight th) -------
__global__ __launch_bounds__(128) void advnet_rowstat(
    const int* __restrict__ u_id, const int* __restrict__ pos_id,
    const float* __restrict__ emb, float* __restrict__ ws) {
  const int r = blockIdx.x;
  const int t = threadIdx.x;

  __shared__ float sA[2], sB[2];
  __shared__ unsigned long long sP[2];
  __shared__ float qrow[64];

  const size_t idx = (size_t)r * NSTRIPS + t;
  const float ms = ws[WS_MPART + idx];
  const float zs = ws[WS_ZPART + idx];
  float M = ms;
  for (int off = 1; off < 64; off <<= 1) M = fmaxf(M, __shfl_xor(M, off, 64));
  if ((t & 63) == 0) sA[t >> 6] = M;
  __syncthreads();
  M = fmaxf(sA[0], sA[1]);
  float z = zs * __expf(ms - M);
  for (int off = 1; off < 64; off <<= 1) z += __shfl_xor(z, off, 64);
  if ((t & 63) == 0) sB[t >> 6] = z;
  __syncthreads();
  const float Z = sB[0] + sB[1];

  // ---- c* = chunk containing the mfma row max ----
  unsigned long long cp = 0ull;
  for (int c = t; c < NCHUNK; c += 128)
    cp = umax64(cp, pack_vn(ws[WS_CMAX + (size_t)r * NCHUNK + c], c));
  for (int off = 1; off < 64; off <<= 1)
    cp = umax64(cp, __shfl_xor(cp, off, 64));
  if ((t & 63) == 0) sP[t >> 6] = cp;
  __syncthreads();
  cp = umax64(sP[0], sP[1]);
  const int cstar = unpack_n(cp);

  if (t < 16) {
    const float4 a = ((const float4*)emb)[(size_t)u_id[r] * 16 + t];
    const float4 c = ((const float4*)emb)[(size_t)pos_id[r] * 16 + t];
    ((float4*)qrow)[t] = make_float4(a.x + c.x, a.y + c.y, a.z + c.z, a.w + c.w);
  }
  __syncthreads();

  // ---- ||q|| (upper-margined) ----
  {
    const float qv = qrow[t & 63];
    float ss = qv * qv;
    for (int off = 1; off < 64; off <<= 1) ss += __shfl_xor(ss, off, 64);
    if (t == 0) ws[WS_QNORM + r] = sqrtf(ss) * 1.00002f;
  }

  // ---- evaluate chunk c* under the HARD bound -> certified v_lb ----
  unsigned long long bp = 0ull;
  const int n = cstar * CHUNK + t;
  if (n < N_COLS) {
    const float s = dot_q_e((const float4*)qrow, (const float4*)emb + (size_t)n * 16);
    if (s != 0.0f && s >= M - G_SPAN_HARD) {
      const uint32_t L = (uint32_t)r * (uint32_t)N_COLS + (uint32_t)n;
      bp = pack_vn(gumbel_at(L) + s, n);
    }
  }
  for (int off = 1; off < 64; off <<= 1)
    bp = umax64(bp, __shfl_xor(bp, off, 64));
  if ((t & 63) == 0) sP[t >> 6] = bp;
  __syncthreads();
  if (t == 0) {
    const unsigned long long best = umax64(sP[0], sP[1]);
    ((unsigned long long*)(ws + WS_BEST))[r] = best;   // seed (reset each call)
    ws[WS_TH + r] = unpack_v(best) - G_MAX_MARGIN;     // tight, still exact
    ws[WS_M + r] = M;
    ws[WS_Z + r] = Z;
    ((int*)ws)[WS_CSTAR + r] = cstar;
  }
}

// ---- K3: scan candidate chunks (16 stripes/row), exact gumbel on survivors --
__global__ __launch_bounds__(128) void advnet_scan(
    const int* __restrict__ u_id, const int* __restrict__ pos_id,
    const float* __restrict__ emb, float* __restrict__ ws) {
  const int bid = blockIdx.x;
  const int r = bid >> 4;
  const int stripe = bid & 15;
  const int t = threadIdx.x;

  __shared__ float qrow[64];
  if (t < 16) {
    const float4 a = ((const float4*)emb)[(size_t)u_id[r] * 16 + t];
    const float4 c = ((const float4*)emb)[(size_t)pos_id[r] * 16 + t];
    ((float4*)qrow)[t] = make_float4(a.x + c.x, a.y + c.y, a.z + c.z, a.w + c.w);
  }
  const float th = ws[WS_TH + r];
  const float bq = ws[WS_QNORM + r] * EPS_B;
  const int cstar = ((const int*)ws)[WS_CSTAR + r];
  __syncthreads();

  unsigned long long bp = 0ull;
  for (int c = stripe; c < NCHUNK; c += SSTRIDE) {
    if (c == cstar) continue;  // covered by K2's seed
    const float cmv = ws[WS_CMAX + (size_t)r * NCHUNK + c];   // mfma max
    const float bb = bq * ws[WS_ENORM + c];                   // certified bound
    if (cmv + bb < th) continue;
    const int n = c * CHUNK + t;
    if (n < N_COLS) {
      const float s = dot_q_e((const float4*)qrow, (const float4*)emb + (size_t)n * 16);
      if (s != 0.0f && s >= th) {
        const uint32_t L = (uint32_t)r * (uint32_t)N_COLS + (uint32_t)n;
        bp = umax64(bp, pack_vn(gumbel_at(L) + s, n));
      }
    }
  }
  if (bp)
    atomicMax((unsigned long long*)(ws + WS_BEST) + r, bp);
}

// --------------------------- K4: finalize outputs ---------------------------
__global__ __launch_bounds__(64) void advnet_final(
    const int* __restrict__ u_id, const int* __restrict__ pos_id,
    const float* __restrict__ emb, const float* __restrict__ ws,
    float* __restrict__ out) {
  const int r = blockIdx.x * 64 + threadIdx.x;
  if (r >= B_ROWS) return;
  const unsigned long long w = ((const unsigned long long*)(ws + WS_BEST))[r];
  const int n = unpack_n(w);
  const float4* qa = (const float4*)emb + (size_t)u_id[r] * 16;
  const float4* qb = (const float4*)emb + (size_t)pos_id[r] * 16;
  const float4* e4 = (const float4*)emb + (size_t)n * 16;
  float s = 0.0f;
#pragma unroll
  for (int k4 = 0; k4 < 16; ++k4) {
    const float4 a = qa[k4], b = qb[k4], e = e4[k4];
    float4 q;
    q.x = a.x + b.x; q.y = a.y + b.y; q.z = a.z + b.z; q.w = a.w + b.w;
    s = fmaf(q.x, e.x, s);
    s = fmaf(q.y, e.y, s);
    s = fmaf(q.z, e.z, s);
    s = fmaf(q.w, e.w, s);
  }
  out[r] = (float)n;
  out[B_ROWS + r] = __expf(s - ws[WS_M + r]) / ws[WS_Z + r];
}

extern "C" void kernel_launch(void* const* d_in, const int* in_sizes, int n_in,
                              void* d_out, int out_size, void* d_ws, size_t ws_size,
                              hipStream_t stream) {
  const int* u_id = (const int*)d_in[0];
  const int* pos_id = (const int*)d_in[1];
  // d_in[2] = train_mask: unused by the reference output
  const float* emb = (const float*)d_in[3];
  float* ws = (float*)d_ws;   // 11.8 MiB used
  float* out = (float*)d_out; // [2048 samples | 2048 probs], f32

  hipLaunchKernelGGL(advnet_enorm, dim3(NCHUNK), dim3(256), 0, stream, emb, ws);
  hipLaunchKernelGGL(advnet_gemm, dim3(ROWG * NSTRIPS), dim3(256), 0, stream,
                     u_id, pos_id, emb, ws);
  hipLaunchKernelGGL(advnet_rowstat, dim3(B_ROWS), dim3(128), 0, stream,
                     u_id, pos_id, emb, ws);
  hipLaunchKernelGGL(advnet_scan, dim3(B_ROWS * SSTRIDE), dim3(128), 0, stream,
                     u_id, pos_id, emb, ws);
  hipLaunchKernelGGL(advnet_final, dim3(B_ROWS / 64), dim3(64), 0, stream,
                     u_id, pos_id, emb, ws, out);
}

// Round 5
// 306.889 us; speedup vs baseline: 8.5455x; 2.1222x over previous
//
#include <hip/hip_runtime.h>
#include <stdint.h>

// Problem constants (from reference):
#define B_ROWS   2048
#define N_COLS   150000
#define NSTRIPS  128
#define CHUNK    128
#define NCHUNK   1172                             // ceil(150000/128), tail has 112 cols
#define ROWG     16                               // 2048/128 row groups

#define NEG_HUGE (-3.0e38f)
// Gumbel hard bounds: u in [tiny, 1-2^-23] -> g in [-4.46966, +15.94238].
#define G_SPAN_HARD  20.6f      // hard winner bound incl. mfma split slack
#define G_MAX_MARGIN 15.944f    // max achievable gumbel + logf-err margin
// Certified |s_canon - s_mfma| <= ||q||2 * ||e||2 * EPS_B
#define EPS_B        2.0e-4f
#define G_FILTER_SLACK 1e-5f    // f32 tie safety on the per-column gumbel filter

// ws layout (float offsets)
#define WS_MPART 0                                       // [B_ROWS][NSTRIPS]
#define WS_ZPART (B_ROWS * NSTRIPS)                      // [B_ROWS][NSTRIPS]
#define WS_CMAX  (2 * B_ROWS * NSTRIPS)                  // [B_ROWS][NCHUNK] mfma chunk max
#define WS_M     (WS_CMAX + B_ROWS * NCHUNK)             // [B_ROWS] anchor max
#define WS_Z     (WS_M + B_ROWS)                         // [B_ROWS] softmax denom
#define WS_VLB   (WS_Z + B_ROWS)                         // [B_ROWS] certified winner lower bound
#define WS_CSTAR (WS_VLB + B_ROWS)                       // [B_ROWS] argmax chunk (int)
#define WS_BEST  (WS_CSTAR + B_ROWS)                     // [B_ROWS] u64 packed best
#define WS_ENORM (WS_BEST + 2 * B_ROWS)                  // [NCHUNK->2048] chunk max ||e||
#define WS_QNORM (WS_ENORM + 2048)                       // [B_ROWS] row ||q||
#define WS_EHI   (WS_QNORM + B_ROWS)                     // bf16-hi table, pre-swizzled, NCHUNK*16KB
#define WS_ELO   (WS_EHI + NCHUNK * 4096)                // bf16-lo table
#define WS_END   (WS_ELO + NCHUNK * 4096)

typedef __attribute__((ext_vector_type(8))) unsigned short ushort8;
typedef __attribute__((ext_vector_type(8))) short short8;
typedef __attribute__((ext_vector_type(4))) float f32x4;

// ---------------- threefry2x32, key = (0, 42) = jax.random.key(42) ----------
// (bit-exact vs reference: verified absmax 0.0 in rounds 1-3)
__device__ __forceinline__ uint32_t rotl32(uint32_t x, int r) {
  return (x << r) | (x >> (32 - r));
}

__device__ __forceinline__ void threefry2x32_k42(uint32_t& x0, uint32_t& x1) {
  const uint32_t ks0 = 0u;
  const uint32_t ks1 = 42u;
  const uint32_t ks2 = 0x1BD11BDAu ^ 0u ^ 42u;
  x0 += ks0; x1 += ks1;
#define TF_R(r) { x0 += x1; x1 = rotl32(x1, (r)); x1 ^= x0; }
  TF_R(13) TF_R(15) TF_R(26) TF_R(6)
  x0 += ks1; x1 += ks2 + 1u;
  TF_R(17) TF_R(29) TF_R(16) TF_R(24)
  x0 += ks2; x1 += ks0 + 2u;
  TF_R(13) TF_R(15) TF_R(26) TF_R(6)
  x0 += ks0; x1 += ks1 + 3u;
  TF_R(17) TF_R(29) TF_R(16) TF_R(24)
  x0 += ks1; x1 += ks2 + 4u;
  TF_R(13) TF_R(15) TF_R(26) TF_R(6)
  x0 += ks2; x1 += ks0 + 5u;
#undef TF_R
}

__device__ __forceinline__ float gumbel_from_bits(uint32_t bits) {
  const uint32_t mant = bits >> 9;
  const float f = __uint_as_float(mant | 0x3f800000u) - 1.0f;  // exact
  const float l1 = mant ? log1pf(f - 1.0f) : -87.33654475055311f;  // ln(u)
  return -__logf(-l1);
}

__device__ __forceinline__ float gumbel_at(uint32_t flat_idx) {
  uint32_t x0 = 0u, x1 = flat_idx;
  threefry2x32_k42(x0, x1);
  return gumbel_from_bits(x0 ^ x1);
}

// order-preserving f32 pack with complemented index (first-occurrence argmax).
__device__ __forceinline__ unsigned long long pack_vn(float v, int n) {
  uint32_t u = __float_as_uint(v);
  u ^= ((uint32_t)((int32_t)u >> 31)) | 0x80000000u;
  return ((unsigned long long)u << 32) | (uint32_t)(0xFFFFFFFFu - (uint32_t)n);
}

__device__ __forceinline__ float unpack_v(unsigned long long p) {
  uint32_t u = (uint32_t)(p >> 32);
  u = (u & 0x80000000u) ? (u ^ 0x80000000u) : ~u;
  return __uint_as_float(u);
}

__device__ __forceinline__ int unpack_n(unsigned long long p) {
  return (int)(0xFFFFFFFFu - (uint32_t)(p & 0xFFFFFFFFull));
}

__device__ __forceinline__ unsigned long long umax64(unsigned long long a,
                                                     unsigned long long b) {
  return a > b ? a : b;
}

// Canonical f32 dot: all exact-path evaluations use THIS chain (consistent).
__device__ __forceinline__ float dot_q_e(const float4* q4, const float4* e4) {
  float s = 0.0f;
#pragma unroll
  for (int k4 = 0; k4 < 16; ++k4) {
    const float4 e = e4[k4];
    const float4 q = q4[k4];
    s = fmaf(q.x, e.x, s);
    s = fmaf(q.y, e.y, s);
    s = fmaf(q.z, e.z, s);
    s = fmaf(q.w, e.w, s);
  }
  return s;
}

// bf16 split helpers (explicit RNE)
__device__ __forceinline__ unsigned short f32_to_bf16_rne(float f) {
  const uint32_t u = __float_as_uint(f);
  return (unsigned short)((u + 0x7fffu + ((u >> 16) & 1u)) >> 16);
}
__device__ __forceinline__ float bf16_to_f32(unsigned short h) {
  return __uint_as_float(((uint32_t)h) << 16);
}

// ---------------- K0a: per-chunk max ||e||_2 (certified bound) --------------
__global__ __launch_bounds__(256) void advnet_enorm(const float* __restrict__ emb,
                                                    float* __restrict__ ws) {
  const int c = blockIdx.x;
  const int t = threadIdx.x;
  const int lane = t & 63;
  const int row = t >> 1;
  const int n = c * CHUNK + row;
  float ss = 0.0f;
  if (n < N_COLS) {
    const float4* p = (const float4*)emb + (size_t)n * 16 + (t & 1) * 8;
#pragma unroll
    for (int i = 0; i < 8; ++i) {
      const float4 v = p[i];
      ss = fmaf(v.x, v.x, ss); ss = fmaf(v.y, v.y, ss);
      ss = fmaf(v.z, v.z, ss); ss = fmaf(v.w, v.w, ss);
    }
  }
  ss += __shfl_xor(ss, 1, 64);
  float mx = ss;
  for (int off = 2; off < 64; off <<= 1) mx = fmaxf(mx, __shfl_xor(mx, off, 64));
  __shared__ float sm[4];
  if (lane == 0) sm[t >> 6] = mx;
  __syncthreads();
  if (t == 0)
    ws[WS_ENORM + c] =
        sqrtf(fmaxf(fmaxf(sm[0], sm[1]), fmaxf(sm[2], sm[3]))) * 1.00002f;
}

// ------- K0b: build pre-swizzled bf16 hi/lo tables (global_load_lds order) --
// Table layout per chunk c: 1024 granules of 16B; granule L = row*8 + gz,
// where gz = kq ^ (row&7). K1's linear global_load_lds then reproduces the
// exact swizzled LDS layout its ds_reads expect.
__global__ __launch_bounds__(256) void advnet_ebuild(const float* __restrict__ emb,
                                                     float* __restrict__ ws) {
  const int c = blockIdx.x;
  const int t = threadIdx.x;
  char* hi_b = (char*)(ws + WS_EHI) + (size_t)c * 16384;
  char* lo_b = (char*)(ws + WS_ELO) + (size_t)c * 16384;
#pragma unroll
  for (int k = 0; k < 4; ++k) {
    const int j = t + 256 * k;          // source granule 0..1023
    const int row = j >> 3, kq = j & 7;
    const int n = c * CHUNK + row;
    ushort8 hi = (ushort8)0, lo = (ushort8)0;
    if (n < N_COLS) {
      const float4* ep = (const float4*)emb + (size_t)n * 16 + kq * 2;
      const float4 a0 = ep[0], a1 = ep[1];
      const float e[8] = {a0.x, a0.y, a0.z, a0.w, a1.x, a1.y, a1.z, a1.w};
#pragma unroll
      for (int j8 = 0; j8 < 8; ++j8) {
        const unsigned short h = f32_to_bf16_rne(e[j8]);
        hi[j8] = h;
        lo[j8] = f32_to_bf16_rne(e[j8] - bf16_to_f32(h));
      }
    }
    const int gz = kq ^ (row & 7);
    *(ushort8*)(hi_b + (size_t)(row * 8 + gz) * 16) = hi;
    *(ushort8*)(lo_b + (size_t)(row * 8 + gz) * 16) = lo;
  }
}

// ---- staging helpers for K1 ----
__device__ __forceinline__ void stage_tbl(const char* tb_hi, const char* tb_lo,
                                          unsigned short* eh, unsigned short* el,
                                          int c, int wave, int lane) {
  const size_t cb = (size_t)c * 16384 + (size_t)(wave * 1024 + lane * 16);
  const int wo = wave * 1024;
#pragma unroll
  for (int i = 0; i < 4; ++i) {
    const int off = i * 4096;
    __builtin_amdgcn_global_load_lds(
        (const __attribute__((address_space(1))) void*)(tb_hi + cb + off),
        (__attribute__((address_space(3))) void*)((char*)eh + wo + off), 16, 0, 0);
    __builtin_amdgcn_global_load_lds(
        (const __attribute__((address_space(1))) void*)(tb_lo + cb + off),
        (__attribute__((address_space(3))) void*)((char*)el + wo + off), 16, 0, 0);
  }
}

__device__ __forceinline__ void stage_conv(const float* __restrict__ emb,
                                           unsigned short* eh, unsigned short* el,
                                           int c, int tid) {
  const int n0 = c * CHUNK;
#pragma unroll
  for (int k = 0; k < 4; ++k) {
    const int p = tid + 256 * k;
    const int row = p >> 3, kq = p & 7;
    const int n = n0 + row;
    ushort8 hi = (ushort8)0, lo = (ushort8)0;
    if (n < N_COLS) {
      const float4* ep = (const float4*)emb + (size_t)n * 16 + kq * 2;
      const float4 a0 = ep[0], a1 = ep[1];
      const float e[8] = {a0.x, a0.y, a0.z, a0.w, a1.x, a1.y, a1.z, a1.w};
#pragma unroll
      for (int j = 0; j < 8; ++j) {
        const unsigned short h = f32_to_bf16_rne(e[j]);
        hi[j] = h;
        lo[j] = f32_to_bf16_rne(e[j] - bf16_to_f32(h));
      }
    }
    const int off = row * 64 + ((kq * 8) ^ ((row & 7) << 3));
    *(ushort8*)&eh[off] = hi;
    *(ushort8*)&el[off] = lo;
  }
}

// ------------------------- K1: MFMA GEMM pass -------------------------------
// 2048 blocks (16 rowgroups x 128 strips), 4 waves. q-fragments hoisted to
// registers (loop-invariant); e-tiles double-buffered; one barrier per chunk.
template <bool TBL>
__global__ __launch_bounds__(256, 2) void advnet_gemm(
    const int* __restrict__ u_id, const int* __restrict__ pos_id,
    const float* __restrict__ emb, float* __restrict__ ws) {
  __shared__ unsigned short eh0[8192], el0[8192], eh1[8192], el1[8192];

  const int tid = threadIdx.x;
  const int bid = blockIdx.x;
  const int rg = bid / NSTRIPS;
  const int strip = bid - rg * NSTRIPS;
  const int wave = tid >> 6;
  const int lane = tid & 63;
  const int lc = lane & 15;
  const int lg = lane >> 4;

  // ---- stage q split into eh0/el0 (temporary), then hoist frags to regs ----
#pragma unroll
  for (int k = 0; k < 4; ++k) {
    const int p = tid + 256 * k;
    const int row = p >> 3, kq = p & 7;
    const int b = rg * 128 + row;
    const float4* ua = (const float4*)emb + (size_t)u_id[b] * 16 + kq * 2;
    const float4* pa = (const float4*)emb + (size_t)pos_id[b] * 16 + kq * 2;
    const float4 a0 = ua[0], a1 = ua[1], c0 = pa[0], c1 = pa[1];
    const float q[8] = {a0.x + c0.x, a0.y + c0.y, a0.z + c0.z, a0.w + c0.w,
                        a1.x + c1.x, a1.y + c1.y, a1.z + c1.z, a1.w + c1.w};
    ushort8 hi, lo;
#pragma unroll
    for (int j = 0; j < 8; ++j) {
      const unsigned short h = f32_to_bf16_rne(q[j]);
      hi[j] = h;
      lo[j] = f32_to_bf16_rne(q[j] - bf16_to_f32(h));
    }
    const int off = row * 64 + ((kq * 8) ^ ((row & 7) << 3));
    *(ushort8*)&eh0[off] = hi;
    *(ushort8*)&el0[off] = lo;
  }
  __syncthreads();

  short8 qh_r[2][2], ql_r[2][2];  // [kh][rt]
#pragma unroll
  for (int kh = 0; kh < 2; ++kh)
#pragma unroll
    for (int rt = 0; rt < 2; ++rt) {
      const int r = wave * 32 + rt * 16 + lc;
      const int off = r * 64 + (((kh * 4 + lg) * 8) ^ ((r & 7) << 3));
      qh_r[kh][rt] = *(const short8*)&eh0[off];
      ql_r[kh][rt] = *(const short8*)&el0[off];
    }
  __syncthreads();  // frag reads done before eh0/el0 reuse

  float m[8], Z[8];
#pragma unroll
  for (int s = 0; s < 8; ++s) { m[s] = NEG_HUGE; Z[s] = 0.0f; }

  const char* tb_hi = (const char*)(ws + WS_EHI);
  const char* tb_lo = (const char*)(ws + WS_ELO);

  if (TBL) stage_tbl(tb_hi, tb_lo, eh0, el0, strip, wave, lane);
  else     stage_conv(emb, eh0, el0, strip, tid);
  __syncthreads();

  int cur = 0;
  for (int c = strip; c < NCHUNK; c += NSTRIPS) {
    unsigned short* EH  = cur ? eh1 : eh0;
    unsigned short* EL  = cur ? el1 : el0;
    unsigned short* EHn = cur ? eh0 : eh1;
    unsigned short* ELn = cur ? el0 : el1;
    if (c + NSTRIPS < NCHUNK) {  // prefetch next chunk (overlaps compute)
      if (TBL) stage_tbl(tb_hi, tb_lo, EHn, ELn, c + NSTRIPS, wave, lane);
      else     stage_conv(emb, EHn, ELn, c + NSTRIPS, tid);
    }

    // ---- MFMA: acc = qh*eh + qh*el + ql*eh over K=64 ----
    f32x4 acc[2][8];
#pragma unroll
    for (int rt = 0; rt < 2; ++rt)
#pragma unroll
      for (int ct = 0; ct < 8; ++ct) acc[rt][ct] = (f32x4){0.f, 0.f, 0.f, 0.f};

#pragma unroll
    for (int kh = 0; kh < 2; ++kh) {
#pragma unroll
      for (int ct = 0; ct < 8; ++ct) {
        const int col = ct * 16 + lc;
        const int off = col * 64 + (((kh * 4 + lg) * 8) ^ ((col & 7) << 3));
        const short8 ehf = *(const short8*)&EH[off];
        const short8 elf = *(const short8*)&EL[off];
#pragma unroll
        for (int rt = 0; rt < 2; ++rt) {
          acc[rt][ct] = __builtin_amdgcn_mfma_f32_16x16x32_bf16(qh_r[kh][rt], ehf, acc[rt][ct], 0, 0, 0);
          acc[rt][ct] = __builtin_amdgcn_mfma_f32_16x16x32_bf16(qh_r[kh][rt], elf, acc[rt][ct], 0, 0, 0);
          acc[rt][ct] = __builtin_amdgcn_mfma_f32_16x16x32_bf16(ql_r[kh][rt], ehf, acc[rt][ct], 0, 0, 0);
        }
      }
    }

    // ---- epilogue: per-lane 8 row-slots x 8 cols: online (m,Z) + chunk max --
    // C layout (m89): col = lane&15, row = (lane>>4)*4 + reg.
#pragma unroll
    for (int rt = 0; rt < 2; ++rt) {
#pragma unroll
      for (int j = 0; j < 4; ++j) {
        const int s = rt * 4 + j;
        float sp[8];
        float cm = NEG_HUGE;
#pragma unroll
        for (int ct = 0; ct < 8; ++ct) {
          const float v = acc[rt][ct][j];
          sp[ct] = (v != 0.0f) ? v : NEG_HUGE;  // score==0 -> -inf mask
          cm = fmaxf(cm, sp[ct]);
        }
        const float nm = fmaxf(m[s], cm);
        float za = 0.0f;
#pragma unroll
        for (int ct = 0; ct < 8; ++ct) za += __expf(sp[ct] - nm);
        Z[s] = Z[s] * __expf(m[s] - nm) + za;
        m[s] = nm;
        float cr = cm;
        cr = fmaxf(cr, __shfl_xor(cr, 1, 64));
        cr = fmaxf(cr, __shfl_xor(cr, 2, 64));
        cr = fmaxf(cr, __shfl_xor(cr, 4, 64));
        cr = fmaxf(cr, __shfl_xor(cr, 8, 64));
        if (lc == 0) {
          const int row = rg * 128 + wave * 32 + rt * 16 + lg * 4 + j;
          ws[WS_CMAX + (size_t)row * NCHUNK + c] = cr;
        }
      }
    }
    __syncthreads();  // drains prefetch loads (had full compute to land) + barrier
    cur ^= 1;
  }

  // ---- merge (m,Z) over the 16 lanes sharing each row; write partials ----
#pragma unroll
  for (int rt = 0; rt < 2; ++rt) {
#pragma unroll
    for (int j = 0; j < 4; ++j) {
      const int s = rt * 4 + j;
      float mi = m[s], Zi = Z[s];
      for (int off = 1; off < 16; off <<= 1) {
        const float om = __shfl_xor(mi, off, 64);
        const float oZ = __shfl_xor(Zi, off, 64);
        const float nm = fmaxf(mi, om);
        Zi = Zi * __expf(mi - nm) + oZ * __expf(om - nm);
        mi = nm;
      }
      if (lc == 0) {
        const int row = rg * 128 + wave * 32 + rt * 16 + lg * 4 + j;
        ws[WS_MPART + (size_t)row * NSTRIPS + strip] = mi;
        ws[WS_ZPART + (size_t)row * NSTRIPS + strip] = Zi;
      }
    }
  }
}

// ------- K2: per-row stats + seed winner from argmax chunk -> v_lb ----------
__global__ __launch_bounds__(128) void advnet_rowstat(
    const int* __restrict__ u_id, const int* __restrict__ pos_id,
    const float* __restrict__ emb, float* __restrict__ ws) {
  const int r = blockIdx.x;
  const int t = threadIdx.x;

  __shared__ float sA[2], sB[2];
  __shared__ unsigned long long sP[2];
  __shared__ float qrow[64];

  const size_t idx = (size_t)r * NSTRIPS + t;
  const float ms = ws[WS_MPART + idx];
  const float zs = ws[WS_ZPART + idx];
  float M = ms;
  for (int off = 1; off < 64; off <<= 1) M = fmaxf(M, __shfl_xor(M, off, 64));
  if ((t & 63) == 0) sA[t >> 6] = M;
  __syncthreads();
  M = fmaxf(sA[0], sA[1]);
  float z = zs * __expf(ms - M);
  for (int off = 1; off < 64; off <<= 1) z += __shfl_xor(z, off, 64);
  if ((t & 63) == 0) sB[t >> 6] = z;
  __syncthreads();
  const float Z = sB[0] + sB[1];

  // ---- c* = chunk containing the mfma row max ----
  unsigned long long cp = 0ull;
  for (int c = t; c < NCHUNK; c += 128)
    cp = umax64(cp, pack_vn(ws[WS_CMAX + (size_t)r * NCHUNK + c], c));
  for (int off = 1; off < 64; off <<= 1)
    cp = umax64(cp, __shfl_xor(cp, off, 64));
  if ((t & 63) == 0) sP[t >> 6] = cp;
  __syncthreads();
  cp = umax64(sP[0], sP[1]);
  const int cstar = unpack_n(cp);

  if (t < 16) {
    const float4 a = ((const float4*)emb)[(size_t)u_id[r] * 16 + t];
    const float4 c = ((const float4*)emb)[(size_t)pos_id[r] * 16 + t];
    ((float4*)qrow)[t] = make_float4(a.x + c.x, a.y + c.y, a.z + c.z, a.w + c.w);
  }
  __syncthreads();

  // ---- ||q|| (upper-margined) ----
  {
    const float qv = qrow[t & 63];
    float ss = qv * qv;
    for (int off = 1; off < 64; off <<= 1) ss += __shfl_xor(ss, off, 64);
    if (t == 0) ws[WS_QNORM + r] = sqrtf(ss) * 1.00002f;
  }

  // ---- evaluate chunk c* under the HARD bound -> certified v_lb ----
  unsigned long long bp = 0ull;
  const int n = cstar * CHUNK + t;
  if (n < N_COLS) {
    const float s = dot_q_e((const float4*)qrow, (const float4*)emb + (size_t)n * 16);
    if (s != 0.0f && s >= M - G_SPAN_HARD) {
      const uint32_t L = (uint32_t)r * (uint32_t)N_COLS + (uint32_t)n;
      bp = pack_vn(gumbel_at(L) + s, n);
    }
  }
  for (int off = 1; off < 64; off <<= 1)
    bp = umax64(bp, __shfl_xor(bp, off, 64));
  if ((t & 63) == 0) sP[t >> 6] = bp;
  __syncthreads();
  if (t == 0) {
    const unsigned long long best = umax64(sP[0], sP[1]);
    ((unsigned long long*)(ws + WS_BEST))[r] = best;   // seed (reset each call)
    ws[WS_VLB + r] = unpack_v(best);                   // certified lower bound
    ws[WS_M + r] = M;
    ws[WS_Z + r] = Z;
    ((int*)ws)[WS_CSTAR + r] = cstar;
  }
}

// ---- K3: gumbel-first candidate scan. 2 blocks/row (parity-split chunks). --
// Column n can win only if g_n > v_lb - (cmax_c + bb_c). Gumbels are pure
// VALU -> evaluate them FIRST; canonical f32 dots only for the ~0-2
// survivors per candidate chunk.
#define SVCAP 2048
__global__ __launch_bounds__(256) void advnet_pick(
    const int* __restrict__ u_id, const int* __restrict__ pos_id,
    const float* __restrict__ emb, float* __restrict__ ws) {
  const int r = blockIdx.x >> 1;
  const int par = blockIdx.x & 1;
  const int t = threadIdx.x;

  __shared__ float qrow[64];
  __shared__ unsigned short cq[600];
  __shared__ float cqg[600];
  __shared__ unsigned int svpk[SVCAP];
  __shared__ float svg[SVCAP];
  __shared__ int cqn, svn;
  __shared__ unsigned long long sred[4];

  if (t == 0) { cqn = 0; svn = 0; }
  if (t < 16) {
    const float4 a = ((const float4*)emb)[(size_t)u_id[r] * 16 + t];
    const float4 c = ((const float4*)emb)[(size_t)pos_id[r] * 16 + t];
    ((float4*)qrow)[t] = make_float4(a.x + c.x, a.y + c.y, a.z + c.z, a.w + c.w);
  }
  const float vlb = ws[WS_VLB + r];
  const float bq = ws[WS_QNORM + r] * EPS_B;
  const int cstar = ((const int*)ws)[WS_CSTAR + r];
  __syncthreads();

  // ---- phase 1: candidate chunks of this parity -> LDS queue ----
  for (int c = par + 2 * t; c < NCHUNK; c += 512) {
    if (c == cstar) continue;  // fully covered by K2's seed
    const float cm = ws[WS_CMAX + (size_t)r * NCHUNK + c];
    const float gth = vlb - cm - bq * ws[WS_ENORM + c];
    if (gth < G_MAX_MARGIN) {
      const int k = atomicAdd(&cqn, 1);
      cq[k] = (unsigned short)c;   // max 586 per parity < 600
      cqg[k] = gth;
    }
  }
  __syncthreads();
  const int nq = cqn;
  const float4* qr4 = (const float4*)qrow;

  unsigned long long bp = 0ull;

  // ---- phase 2: 8 chunks/iter gumbel filter; drain survivors as needed ----
  for (int base = 0; base < nq; base += 8) {
    if (svn > SVCAP - 1024) {  // uniform decision (svn stable since last sync)
      __syncthreads();
      const int cnt = svn;
      for (int k = t; k < cnt; k += 256) {
        const int n = (int)svpk[k];
        const float s = dot_q_e(qr4, (const float4*)emb + (size_t)n * 16);
        if (s != 0.0f) bp = umax64(bp, pack_vn(svg[k] + s, n));
      }
      __syncthreads();
      if (t == 0) svn = 0;
      __syncthreads();
    }
#pragma unroll
    for (int u = 0; u < 4; ++u) {
      const int idx = t + 256 * u;
      const int slot = base + (idx >> 7);
      if (slot < nq) {
        const int n = (int)cq[slot] * CHUNK + (idx & 127);
        if (n < N_COLS) {
          const float g = gumbel_at((uint32_t)r * (uint32_t)N_COLS + (uint32_t)n);
          if (g > cqg[slot] - G_FILTER_SLACK) {
            const int k = atomicAdd(&svn, 1);
            if (k < SVCAP) { svpk[k] = (unsigned)n; svg[k] = g; }
          }
        }
      }
    }
    __syncthreads();  // pushes visible; svn settled for next-iter check
  }

  // ---- final drain ----
  {
    const int cnt = svn < SVCAP ? svn : SVCAP;
    for (int k = t; k < cnt; k += 256) {
      const int n = (int)svpk[k];
      const float s = dot_q_e(qr4, (const float4*)emb + (size_t)n * 16);
      if (s != 0.0f) bp = umax64(bp, pack_vn(svg[k] + s, n));
    }
  }

  // ---- block reduce + merge into per-row best ----
  for (int off = 1; off < 64; off <<= 1)
    bp = umax64(bp, __shfl_xor(bp, off, 64));
  if ((t & 63) == 0) sred[t >> 6] = bp;
  __syncthreads();
  if (t == 0) {
    const unsigned long long b =
        umax64(umax64(sred[0], sred[1]), umax64(sred[2], sred[3]));
    if (b) atomicMax((unsigned long long*)(ws + WS_BEST) + r, b);
  }
}

// --------------------------- K4: finalize outputs ---------------------------
__global__ __launch_bounds__(64) void advnet_final(
    const int* __restrict__ u_id, const int* __restrict__ pos_id,
    const float* __restrict__ emb, const float* __restrict__ ws,
    float* __restrict__ out) {
  const int r = blockIdx.x * 64 + threadIdx.x;
  if (r >= B_ROWS) return;
  const unsigned long long w = ((const unsigned long long*)(ws + WS_BEST))[r];
  const int n = unpack_n(w);
  const float4* qa = (const float4*)emb + (size_t)u_id[r] * 16;
  const float4* qb = (const float4*)emb + (size_t)pos_id[r] * 16;
  const float4* e4 = (const float4*)emb + (size_t)n * 16;
  float s = 0.0f;
#pragma unroll
  for (int k4 = 0; k4 < 16; ++k4) {
    const float4 a = qa[k4], b = qb[k4], e = e4[k4];
    float4 q;
    q.x = a.x + b.x; q.y = a.y + b.y; q.z = a.z + b.z; q.w = a.w + b.w;
    s = fmaf(q.x, e.x, s);
    s = fmaf(q.y, e.y, s);
    s = fmaf(q.z, e.z, s);
    s = fmaf(q.w, e.w, s);
  }
  out[r] = (float)n;
  out[B_ROWS + r] = __expf(s - ws[WS_M + r]) / ws[WS_Z + r];
}

extern "C" void kernel_launch(void* const* d_in, const int* in_sizes, int n_in,
                              void* d_out, int out_size, void* d_ws, size_t ws_size,
                              hipStream_t stream) {
  const int* u_id = (const int*)d_in[0];
  const int* pos_id = (const int*)d_in[1];
  // d_in[2] = train_mask: unused by the reference output
  const float* emb = (const float*)d_in[3];
  float* ws = (float*)d_ws;
  float* out = (float*)d_out;  // [2048 samples | 2048 probs], f32

  const size_t need = (size_t)WS_END * 4;  // ~47.9 MiB with tables
  const bool tbl = ws_size >= need;        // deterministic across calls

  advnet_enorm<<<dim3(NCHUNK), dim3(256), 0, stream>>>(emb, ws);
  if (tbl) {
    advnet_ebuild<<<dim3(NCHUNK), dim3(256), 0, stream>>>(emb, ws);
    advnet_gemm<true><<<dim3(ROWG * NSTRIPS), dim3(256), 0, stream>>>(
        u_id, pos_id, emb, ws);
  } else {
    advnet_gemm<false><<<dim3(ROWG * NSTRIPS), dim3(256), 0, stream>>>(
        u_id, pos_id, emb, ws);
  }
  advnet_rowstat<<<dim3(B_ROWS), dim3(128), 0, stream>>>(u_id, pos_id, emb, ws);
  advnet_pick<<<dim3(B_ROWS * 2), dim3(256), 0, stream>>>(u_id, pos_id, emb, ws);
  advnet_final<<<dim3(B_ROWS / 64), dim3(64), 0, stream>>>(u_id, pos_id, emb, ws, out);
}